// Round 1
// baseline (438.500 us; speedup 1.0000x reference)
//
#include <hip/hip_runtime.h>

// EMA over frames axis: y[n] = w*x[n] + (1-w)*y[n-1], y[-1] = initial_state.
// input:  (16, 8, 256, 2048) fp32, frames contiguous -> 32768 sequences x 2048.
// weight: (8, 256) broadcast over batch -> seq s uses weight[s & 2047].
//
// Strategy: 1 wave (64 lanes) per sequence. Lane owns 32 contiguous frames
// (8 x float4). Linear-recurrence parallel scan: transform (A,B) with
// y_out = A*y_in + B composes as (A2,B2)o(A1,B1) = (A2*A1, A2*B1+B2).
// Local pass -> wave Kogge-Stone shuffle scan -> exclusive transform applied
// to initial_state -> second pass over register-resident x -> float4 stores.

#define N_FRAMES 2048
#define FRAMES_PER_LANE 32   // 2048 / 64
#define VEC_PER_LANE 8       // 32 / 4

__global__ __launch_bounds__(64) void ema_scan_kernel(
    const float* __restrict__ x,
    const float* __restrict__ y0,
    const float* __restrict__ wgt,
    float* __restrict__ out) {
  const int s = blockIdx.x;        // sequence id in [0, 32768)
  const int lane = threadIdx.x;    // 0..63

  // per-(res,bin) smoothing coeff, clamped to [0,1]
  const float w_raw = wgt[s & 2047];
  const float w = fminf(fmaxf(w_raw, 0.0f), 1.0f);
  const float a = 1.0f - w;

  // load this lane's 32 contiguous frames (wave covers 8 KiB contiguously)
  const float4* in4 =
      reinterpret_cast<const float4*>(x + (size_t)s * N_FRAMES) +
      lane * VEC_PER_LANE;
  float4 v[VEC_PER_LANE];
#pragma unroll
  for (int k = 0; k < VEC_PER_LANE; ++k) v[k] = in4[k];

  // local scan assuming zero incoming state -> B of this lane's transform
  float b = 0.0f;
#pragma unroll
  for (int k = 0; k < VEC_PER_LANE; ++k) {
    b = fmaf(a, b, w * v[k].x);
    b = fmaf(a, b, w * v[k].y);
    b = fmaf(a, b, w * v[k].z);
    b = fmaf(a, b, w * v[k].w);
  }
  // A = a^32
  const float a2 = a * a;
  const float a4 = a2 * a2;
  const float a8 = a4 * a4;
  const float a16 = a8 * a8;
  const float a32 = a16 * a16;

  // inclusive Kogge-Stone scan of (A, B) across the 64-lane wave
  float Ai = a32;
  float Bi = b;
#pragma unroll
  for (int d = 1; d < 64; d <<= 1) {
    float Ap = __shfl_up(Ai, d, 64);
    float Bp = __shfl_up(Bi, d, 64);
    if (lane >= d) {
      Bi = fmaf(Ai, Bp, Bi);  // cur o prev: B = A_cur*B_prev + B_cur
      Ai = Ai * Ap;
    }
  }

  // incoming state for this lane = exclusive transform applied to y0
  const float Ae = __shfl_up(Ai, 1, 64);
  const float Be = __shfl_up(Bi, 1, 64);
  const float ys = y0[s];
  float y = (lane == 0) ? ys : fmaf(Ae, ys, Be);

  // second pass: emit the 32 outputs
  float4* o4 = reinterpret_cast<float4*>(out + (size_t)s * N_FRAMES) +
               lane * VEC_PER_LANE;
#pragma unroll
  for (int k = 0; k < VEC_PER_LANE; ++k) {
    float4 r;
    y = fmaf(a, y, w * v[k].x); r.x = y;
    y = fmaf(a, y, w * v[k].y); r.y = y;
    y = fmaf(a, y, w * v[k].z); r.z = y;
    y = fmaf(a, y, w * v[k].w); r.w = y;
    o4[k] = r;
  }
}

extern "C" void kernel_launch(void* const* d_in, const int* in_sizes, int n_in,
                              void* d_out, int out_size, void* d_ws, size_t ws_size,
                              hipStream_t stream) {
  const float* x   = (const float*)d_in[0];  // (16,8,256,2048)
  const float* y0  = (const float*)d_in[1];  // (16,8,256)
  const float* wgt = (const float*)d_in[2];  // (8,256)
  float* out = (float*)d_out;

  const int n_seq = 16 * 8 * 256;  // 32768 sequences
  ema_scan_kernel<<<dim3(n_seq), dim3(64), 0, stream>>>(x, y0, wgt, out);
}

// Round 2
// 431.114 us; speedup vs baseline: 1.0171x; 1.0171x over previous
//
#include <hip/hip_runtime.h>

// EMA over frames: y[n] = w*x[n] + (1-w)*y[n-1], y[-1] = initial_state.
// input (16,8,256,2048) fp32 -> 32768 sequences x 2048 frames, frames contiguous.
//
// One wave per sequence, 4 waves (4 sequences) per 256-thread block.
// Coalesced ownership: lane i holds float4 i of each 1-KiB chunk, i.e. frames
// 256k + 4i .. 4i+3 (4 CONSECUTIVE frames -> a valid segment transform).
// Decay a = 1-w is wave-uniform, so segment decay a^4 is uniform: the wave
// scan needs no A-component. Kogge-Stone on b with uniform multipliers
// a^(4d): 1 shuffle + 1 FMA per step, 6 steps, 8 independent chunk scans.
// Scalar carry chain across the 8 chunks: carry = a^256*carry + b[lane63].

#define N_FRAMES 2048
#define CHUNKS 8           // 2048 / (64 lanes * 4)
#define SEQ_PER_BLOCK 4

__global__ __launch_bounds__(256) void ema_scan_kernel(
    const float* __restrict__ x,
    const float* __restrict__ y0,
    const float* __restrict__ wgt,
    float* __restrict__ out) {
  const int lane = threadIdx.x & 63;
  const int wid  = threadIdx.x >> 6;
  const int s = blockIdx.x * SEQ_PER_BLOCK + wid;   // sequence id

  const float w_raw = wgt[s & 2047];                // (res,bin) broadcast over batch
  const float w = fminf(fmaxf(w_raw, 0.0f), 1.0f);
  const float a = 1.0f - w;

  // uniform powers of a
  const float a4   = (a * a) * (a * a);  // per-segment decay
  const float A1   = a4;                 // a^4
  const float A2   = A1 * A1;            // a^8
  const float A4   = A2 * A2;            // a^16
  const float A8   = A4 * A4;            // a^32
  const float A16  = A8 * A8;            // a^64
  const float A32  = A16 * A16;          // a^128
  const float a256 = A32 * A32;          // per-chunk decay

  // per-lane power a^(4*lane) via bit-select (works for a == 0 too)
  float powl = 1.0f;
  powl *= (lane & 1)  ? A1  : 1.0f;
  powl *= (lane & 2)  ? A2  : 1.0f;
  powl *= (lane & 4)  ? A4  : 1.0f;
  powl *= (lane & 8)  ? A8  : 1.0f;
  powl *= (lane & 16) ? A16 : 1.0f;
  powl *= (lane & 32) ? A32 : 1.0f;

  const float4* in4 = reinterpret_cast<const float4*>(x + (size_t)s * N_FRAMES);
  float4*       o4  = reinterpret_cast<float4*>(out + (size_t)s * N_FRAMES);

  // coalesced loads: per instruction the wave covers 1 KiB contiguous
  float4 v[CHUNKS];
#pragma unroll
  for (int k = 0; k < CHUNKS; ++k) v[k] = in4[k * 64 + lane];

  // local 4-frame segment result applied to zero incoming state
  float b[CHUNKS];
#pragma unroll
  for (int k = 0; k < CHUNKS; ++k) {
    float t = w * v[k].x;
    t = fmaf(a, t, w * v[k].y);
    t = fmaf(a, t, w * v[k].z);
    t = fmaf(a, t, w * v[k].w);
    b[k] = t;
  }

  // inclusive wave scans (independent across chunks -> ILP hides shuffle latency)
#pragma unroll
  for (int k = 0; k < CHUNKS; ++k) {
    float t = b[k];
    float p;
    p = __shfl_up(t, 1, 64);  if (lane >= 1)  t = fmaf(A1,  p, t);
    p = __shfl_up(t, 2, 64);  if (lane >= 2)  t = fmaf(A2,  p, t);
    p = __shfl_up(t, 4, 64);  if (lane >= 4)  t = fmaf(A4,  p, t);
    p = __shfl_up(t, 8, 64);  if (lane >= 8)  t = fmaf(A8,  p, t);
    p = __shfl_up(t, 16, 64); if (lane >= 16) t = fmaf(A16, p, t);
    p = __shfl_up(t, 32, 64); if (lane >= 32) t = fmaf(A32, p, t);
    b[k] = t;
  }

  // carry chain over chunks + coalesced output
  float carry = y0[s];
#pragma unroll
  for (int k = 0; k < CHUNKS; ++k) {
    float excl = __shfl_up(b[k], 1, 64);
    if (lane == 0) excl = 0.0f;
    float y = fmaf(powl, carry, excl);   // state entering this lane's segment
    float4 r;
    y = fmaf(a, y, w * v[k].x); r.x = y;
    y = fmaf(a, y, w * v[k].y); r.y = y;
    y = fmaf(a, y, w * v[k].z); r.z = y;
    y = fmaf(a, y, w * v[k].w); r.w = y;
    o4[k * 64 + lane] = r;
    carry = fmaf(a256, carry, __shfl(b[k], 63, 64));  // chunk-total advance
  }
}

extern "C" void kernel_launch(void* const* d_in, const int* in_sizes, int n_in,
                              void* d_out, int out_size, void* d_ws, size_t ws_size,
                              hipStream_t stream) {
  const float* x   = (const float*)d_in[0];  // (16,8,256,2048)
  const float* y0  = (const float*)d_in[1];  // (16,8,256)
  const float* wgt = (const float*)d_in[2];  // (8,256)
  float* out = (float*)d_out;

  const int n_seq = 16 * 8 * 256;            // 32768
  ema_scan_kernel<<<dim3(n_seq / SEQ_PER_BLOCK), dim3(256), 0, stream>>>(x, y0, wgt, out);
}